// Round 3
// baseline (746.160 us; speedup 1.0000x reference)
//
#include <hip/hip_runtime.h>

#define Bsz 4096
#define Fsz 32
#define Dsz 64
#define Psz 496
#define RPW 64      // b-rows per wave
#define WPB 4       // waves per block (256 threads)

// One wave owns one pair p and RPW consecutive b-rows.
// Lane e (0..63) holds the full column W[p][:, e] in 64 VGPRs.
// Per row: vi[b] is wave-uniform -> scalar loads (SGPRs); 64 v_fmac with
// SGPR src0; single sequential fmaf chain keeps bitwise accumulation order
// identical to the previous (absmax==0.0) kernel.
__global__ __launch_bounds__(256)
void bilinear_wreg_kernel(const float* __restrict__ in,
                          const float* __restrict__ W,
                          float* __restrict__ out)
{
    const int p    = blockIdx.x;
    const int tid  = threadIdx.x;
    const int lane = tid & 63;

    // Wave-uniform base row. readfirstlane forces it into an SGPR so the
    // vi loads below are provably uniform -> s_load_dwordx16.
    const int bb0 = __builtin_amdgcn_readfirstlane(
                        blockIdx.y * (RPW * WPB) + (tid >> 6) * RPW);

    // Decode pair p -> (i, j), matching np.triu_indices(F, k=1) order.
    int i = 0, rem = p;
    while (rem >= Fsz - 1 - i) { rem -= Fsz - 1 - i; ++i; }
    const int j = i + 1 + rem;

    // Load W[p] column 'lane' into registers: 64 coalesced dword loads
    // (256 B per instruction across the wave). One-time cost per wave,
    // amortized over RPW rows.
    float w[Dsz];
    {
        const float* Wp = W + (size_t)p * (Dsz * Dsz) + lane;
#pragma unroll
        for (int d = 0; d < Dsz; ++d) w[d] = Wp[(size_t)d * Dsz];
    }

    const float* __restrict__ vi0 = in  + ((size_t)bb0 * Fsz + i) * Dsz;         // uniform
    const float* __restrict__ vj0 = in  + ((size_t)bb0 * Fsz + j) * Dsz + lane;  // per-lane
    float*       __restrict__ op0 = out + ((size_t)bb0 * Psz + p) * Dsz + lane;  // per-lane

#pragma unroll 1
    for (int r = 0; r < RPW; ++r) {
        const float* vi  = vi0 + (size_t)r * (Fsz * Dsz);   // wave-uniform address
        const float  vjv = vj0[(size_t)r * (Fsz * Dsz)];    // 256 B coalesced vector load

        // Whole vi row into scalar registers (4x s_load_dwordx16 expected).
        float s[Dsz];
#pragma unroll
        for (int d = 0; d < Dsz; ++d) s[d] = vi[d];

        // 64 v_fmac_f32 acc, s[d], w[d] — zero LDS traffic.
        float acc = 0.0f;
#pragma unroll
        for (int d = 0; d < Dsz; ++d) acc = fmaf(s[d], w[d], acc);

        // 256 B contiguous per wave-instruction; nontemporal to keep the
        // 520 MB output stream from evicting the L2-resident 'in' tensor.
        __builtin_nontemporal_store(acc * vjv, op0 + (size_t)r * (Psz * Dsz));
    }
}

extern "C" void kernel_launch(void* const* d_in, const int* in_sizes, int n_in,
                              void* d_out, int out_size, void* d_ws, size_t ws_size,
                              hipStream_t stream) {
    const float* in  = (const float*)d_in[0];
    const float* W   = (const float*)d_in[1];
    float*       out = (float*)d_out;

    dim3 grid(Psz, Bsz / (RPW * WPB));   // (496, 16)
    bilinear_wreg_kernel<<<grid, 256, 0, stream>>>(in, W, out);
}